// Round 5
// baseline (5919.823 us; speedup 1.0000x reference)
//
#include <hip/hip_runtime.h>
#include <cstdint>
#include <cstddef>

#define BB 512   // batch
#define TT 512   // seq len
#define HH 100   // hidden
#define G4 400   // 4*H

// ---------------------------------------------------------------------------
// Recurrent kernel: full 512 steps of one layer in one launch.
// grid = 256 blocks x 448 threads, 1 block/CU (launch_bounds(448,1) -> VGPR
// cap 256, enough for 200 register-resident weights; round-4's (448,2) capped
// at 128 and forced per-step weight remat from L2).
// Thread (p = tid>>1, e = tid&1): owns gate-rows {p, p+200} of elem 2*bid+e.
// Rows are gate-major (i:0-99, f:100-199, g:200-299, o:300-399), so r0 is
// always sigmoid and r1 is tanh iff p<100 -> activations applied IN PHASE 1
// (7 waves busy) leaving phase2 with a single exp.
// Weights are gathered from an LDS staging copy of Whh that is then fully
// overwritten (reused as hbuf/gsh) => compiler cannot remat the gathers.
// All global reads (xc, dmask, x) prefetched one full step ahead.
// ---------------------------------------------------------------------------
template<bool IS_L0, bool WRITE_DROP>
__global__ __launch_bounds__(448, 1)
void rec_kernel(const float* __restrict__ x,       // [B][T] (layer0 input, IN=1)
                const float* __restrict__ xc,      // [T][B][400] (layers>0)
                const float* __restrict__ Whh_l,   // [400][100]
                const float* __restrict__ Wih0,    // [400] (layer0)
                const float* __restrict__ bih_l,   // [400] (layer0)
                const float* __restrict__ bhh_l,   // [400] (layer0)
                const float* __restrict__ dmask_l, // [B][T][100] (if WRITE_DROP)
                float* __restrict__ hdrop,         // [T][B][100] (if WRITE_DROP)
                float* __restrict__ st_h,          // [B][100]
                float* __restrict__ st_c)          // [B][100]
{
    __shared__ float sh[G4 * HH];   // 160,000 B: weight staging, then hbuf+gsh

    const int tid = threadIdx.x;
    const int p   = tid >> 1;                  // 0..223
    const int e   = tid & 1;
    const bool rowok = (p < 200);
    const int pc  = rowok ? p : 199;
    const int r0  = pc;                        // i|f row (sigmoid)
    const int r1  = pc + 200;                  // g|o row (tanh if p<100)
    const int b   = blockIdx.x * 2 + e;

    // --- stage Whh into LDS (coalesced float4) ---
    {
        const float4* src = (const float4*)Whh_l;
        float4* dst = (float4*)sh;
        for (int i = tid; i < G4 * HH / 4; i += 448) dst[i] = src[i];
    }
    __syncthreads();

    // --- gather this thread's two gate-rows into registers ---
    float4 wf0[25], wf1[25];
    {
        const float4* s0 = (const float4*)&sh[r0 * HH];
        const float4* s1 = (const float4*)&sh[r1 * HH];
        #pragma unroll
        for (int m = 0; m < 25; ++m) { wf0[m] = s0[m]; wf1[m] = s1[m]; }
    }
    __syncthreads();

    // --- clobber ALL of sh: kills remat-from-LDS, zero-inits hbuf ---
    for (int i = tid; i < G4 * HH; i += 448) sh[i] = 0.f;

    // aliased layout: hbuf[buf2][e2][112] = sh[0..448), gsh[e2][400] = sh[448..1248)
    float* gshp = sh + 448;

    float wx0 = 0.f, wx1 = 0.f, bs0 = 0.f, bs1 = 0.f;
    if (IS_L0) {
        wx0 = Wih0[r0];  bs0 = bih_l[r0] + bhh_l[r0];
        wx1 = Wih0[r1];  bs1 = bih_l[r1] + bhh_l[r1];
    }

    const bool isP2 = (tid < 200);             // phase2: (e, jj=p), p<100
    const int jj  = p;
    const bool sel = (p < HH);                 // r1 is a g-row -> tanh
    float c2 = 0.f, hlast = 0.f;

    __syncthreads();

    // --- prefetch t = 0 ---
    float gin0 = 0.f, gin1 = 0.f, xv = 0.f, mk = 0.f;
    if (IS_L0) {
        xv = x[(size_t)b * TT];
    } else {
        gin0 = xc[(size_t)b * G4 + r0];
        gin1 = xc[(size_t)b * G4 + r1];
    }
    if (WRITE_DROP && isP2) mk = dmask_l[(size_t)b * TT * HH + jj];

    int cur = 0;
    for (int t = 0; t < TT; ++t) {
        const int tn = (t + 1 < TT) ? (t + 1) : t;

        // --- issue prefetches for t+1 ---
        float nxv = 0.f, ngin0 = 0.f, ngin1 = 0.f, nmk = 0.f;
        if (IS_L0) {
            nxv = x[(size_t)b * TT + tn];
        } else {
            const size_t base = (size_t)tn * (BB * G4) + (size_t)b * G4;
            ngin0 = xc[base + r0];
            ngin1 = xc[base + r1];
        }
        if (WRITE_DROP && isP2) nmk = dmask_l[((size_t)b * TT + tn) * HH + jj];

        if (IS_L0) {
            gin0 = fmaf(xv, wx0, bs0);
            gin1 = fmaf(xv, wx1, bs1);
        }

        // --- phase 1: two gate-row dots over own elem's h + activation ---
        float a0 = 0.f, a0b = 0.f, a1 = 0.f, a1b = 0.f;
        {
            const float4* hp = (const float4*)&sh[cur * 224 + e * 112];
            #pragma unroll
            for (int m = 0; m < 25; ++m) {
                const float4 hv = hp[m];
                a0  = fmaf(wf0[m].x, hv.x, a0);
                a0b = fmaf(wf0[m].y, hv.y, a0b);
                a0  = fmaf(wf0[m].z, hv.z, a0);
                a0b = fmaf(wf0[m].w, hv.w, a0b);
                a1  = fmaf(wf1[m].x, hv.x, a1);
                a1b = fmaf(wf1[m].y, hv.y, a1b);
                a1  = fmaf(wf1[m].z, hv.z, a1);
                a1b = fmaf(wf1[m].w, hv.w, a1b);
            }
        }
        const float pre0 = a0 + a0b + gin0;
        const float pre1 = a1 + a1b + gin1;
        const float E0   = __expf(-pre0);
        const float act0 = 1.f / (1.f + E0);                   // sigmoid (i|f)
        const float E1   = __expf(sel ? (pre1 + pre1) : (-pre1));
        const float rr   = 1.f / (1.f + E1);
        const float act1 = sel ? fmaf(-2.f, rr, 1.f) : rr;     // tanh(g) | sig(o)
        if (rowok) {
            gshp[e * G4 + pc]       = act0;
            gshp[e * G4 + pc + 200] = act1;
        }
        __syncthreads();

        // --- phase 2: combine activated gates, update c/h ---
        const int nxt = cur ^ 1;
        if (isP2) {
            const float i_ = gshp[e * G4 + jj];
            const float f_ = gshp[e * G4 + 100 + jj];
            const float g_ = gshp[e * G4 + 200 + jj];
            const float o_ = gshp[e * G4 + 300 + jj];
            c2 = fmaf(f_, c2, i_ * g_);
            const float Ec = __expf(c2 + c2);
            const float th = 1.f - 2.f / (Ec + 1.f);
            const float h  = o_ * th;
            hlast = h;
            sh[nxt * 224 + e * 112 + jj] = h;
            if (WRITE_DROP)
                hdrop[((size_t)t * BB + b) * HH + jj] = h * mk * 2.f;
        }
        __syncthreads();
        cur = nxt;
        gin0 = ngin0; gin1 = ngin1; xv = nxv; mk = nmk;
    }

    if (isP2) {
        st_h[(size_t)b * HH + jj] = hlast;
        st_c[(size_t)b * HH + jj] = c2;
    }
}

// ---------------------------------------------------------------------------
// Input-contribution GEMM for layers 1..3 (round-2 design: 128x128 tile,
// 8x8 microtile, measured ~200 us equivalent vs 280 us for 128x64):
// xc[m][n] = sum_k A[m][k]*W[n][k] + (bih[n]+bhh[n]), M=T*B=262144, N=400, K=100
// grid (4, 2048): the 4 n-tiles sharing an A-tile are dispatch-adjacent.
// ---------------------------------------------------------------------------
__global__ __launch_bounds__(256)
void xc_gemm(const float* __restrict__ A,     // [M][100]
             const float* __restrict__ W,     // [400][100]
             const float* __restrict__ bih_l, // [400]
             const float* __restrict__ bhh_l, // [400]
             float* __restrict__ xc)          // [M][400]
{
    __shared__ float At[HH][132];
    __shared__ float Bt[HH][132];

    const int tid = threadIdx.x;
    const int n0  = blockIdx.x * 128;
    const size_t m0 = (size_t)blockIdx.y * 128;

    for (int s = tid; s < 128 * HH; s += 256) {
        const int r = s / HH, k = s - r * HH;
        At[k][r] = A[(m0 + r) * HH + k];
        const int col = n0 + r;
        Bt[k][r] = (col < G4) ? W[(size_t)col * HH + k] : 0.f;
    }
    __syncthreads();

    const int tx = tid & 15, ty = tid >> 4;
    float acc[8][8];
    #pragma unroll
    for (int i = 0; i < 8; ++i)
        #pragma unroll
        for (int j = 0; j < 8; ++j) acc[i][j] = 0.f;

    #pragma unroll 2
    for (int k = 0; k < HH; ++k) {
        const float4 a0 = *(const float4*)&At[k][ty * 4];
        const float4 a1 = *(const float4*)&At[k][64 + ty * 4];
        const float4 b0 = *(const float4*)&Bt[k][tx * 4];
        const float4 b1 = *(const float4*)&Bt[k][64 + tx * 4];
        const float av[8] = {a0.x, a0.y, a0.z, a0.w, a1.x, a1.y, a1.z, a1.w};
        const float bv[8] = {b0.x, b0.y, b0.z, b0.w, b1.x, b1.y, b1.z, b1.w};
        #pragma unroll
        for (int i = 0; i < 8; ++i)
            #pragma unroll
            for (int j = 0; j < 8; ++j)
                acc[i][j] = fmaf(av[i], bv[j], acc[i][j]);
    }

    const int c0 = n0 + tx * 4;
    const int c1 = n0 + 64 + tx * 4;
    float4 biasA = {0,0,0,0}, biasB = {0,0,0,0};
    if (c0 < G4) {
        const float4 u = *(const float4*)&bih_l[c0];
        const float4 v = *(const float4*)&bhh_l[c0];
        biasA = {u.x + v.x, u.y + v.y, u.z + v.z, u.w + v.w};
    }
    if (c1 < G4) {
        const float4 u = *(const float4*)&bih_l[c1];
        const float4 v = *(const float4*)&bhh_l[c1];
        biasB = {u.x + v.x, u.y + v.y, u.z + v.z, u.w + v.w};
    }

    #pragma unroll
    for (int i = 0; i < 8; ++i) {
        const size_t row = m0 + ((i < 4) ? ty * 4 + i : 64 + ty * 4 + (i - 4));
        if (c0 < G4) {
            float4 o = {acc[i][0] + biasA.x, acc[i][1] + biasA.y,
                        acc[i][2] + biasA.z, acc[i][3] + biasA.w};
            *(float4*)&xc[row * G4 + c0] = o;
        }
        if (c1 < G4) {
            float4 o = {acc[i][4] + biasB.x, acc[i][5] + biasB.y,
                        acc[i][6] + biasB.z, acc[i][7] + biasB.w};
            *(float4*)&xc[row * G4 + c1] = o;
        }
    }
}

// ---------------------------------------------------------------------------
__global__ __launch_bounds__(256)
void out_kernel(const float* __restrict__ st_h3,  // [B][100]
                const float* __restrict__ Wout,   // [100]
                const float* __restrict__ bout,   // [1]
                float* __restrict__ out)          // [B]
{
    const int b = blockIdx.x * 256 + threadIdx.x;
    if (b < BB) {
        float sum = bout[0];
        #pragma unroll 4
        for (int k = 0; k < HH; ++k)
            sum = fmaf(st_h3[(size_t)b * HH + k], Wout[k], sum);
        out[b] = sum;
    }
}

// ---------------------------------------------------------------------------
extern "C" void kernel_launch(void* const* d_in, const int* in_sizes, int n_in,
                              void* d_out, int out_size, void* d_ws, size_t ws_size,
                              hipStream_t stream)
{
    const float* x     = (const float*)d_in[0];  // [512][512][1]
    const float* Wih0  = (const float*)d_in[1];  // [400][1]
    const float* WihR  = (const float*)d_in[2];  // [3][400][100]
    const float* Whh   = (const float*)d_in[3];  // [4][400][100]
    const float* bih   = (const float*)d_in[4];  // [4][400]
    const float* bhh   = (const float*)d_in[5];  // [4][400]
    const float* Wout  = (const float*)d_in[6];  // [1][100]
    const float* bout  = (const float*)d_in[7];  // [1]
    const float* dmask = (const float*)d_in[8];  // [3][512][512][100]
    float* out = (float*)d_out;

    // ws layout (floats): ~526 MB of the 1200 MB workspace
    float* ws    = (float*)d_ws;
    float* xcb   = ws;                                  // T*B*400
    float* hdrop = xcb + (size_t)TT * BB * G4;          // T*B*100
    float* sth   = hdrop + (size_t)TT * BB * HH;        // 4*B*100
    float* stc   = sth + (size_t)4 * BB * HH;           // 4*B*100

    const dim3 rgrid(BB / 2), rblk(448);
    const dim3 ggrid(4, (TT * BB) / 128), gblk(256);

    // layer 0 (input dim 1 fused into rec)
    rec_kernel<true, true><<<rgrid, rblk, 0, stream>>>(
        x, nullptr, Whh, Wih0, bih, bhh, dmask,
        hdrop, sth, stc);
    // layers 1..3
    for (int l = 1; l < 4; ++l) {
        xc_gemm<<<ggrid, gblk, 0, stream>>>(
            hdrop, WihR + (size_t)(l - 1) * G4 * HH,
            bih + l * G4, bhh + l * G4, xcb);
        if (l < 3) {
            rec_kernel<false, true><<<rgrid, rblk, 0, stream>>>(
                nullptr, xcb, Whh + (size_t)l * G4 * HH,
                nullptr, nullptr, nullptr,
                dmask + (size_t)l * BB * TT * HH,
                hdrop, sth + (size_t)l * BB * HH, stc + (size_t)l * BB * HH);
        } else {
            rec_kernel<false, false><<<rgrid, rblk, 0, stream>>>(
                nullptr, xcb, Whh + (size_t)l * G4 * HH,
                nullptr, nullptr, nullptr,
                nullptr,
                nullptr, sth + (size_t)l * BB * HH, stc + (size_t)l * BB * HH);
        }
    }
    out_kernel<<<dim3(2), dim3(256), 0, stream>>>(sth + (size_t)3 * BB * HH, Wout, bout, out);
}

// Round 6
// 3577.654 us; speedup vs baseline: 1.6547x; 1.6547x over previous
//
#include <hip/hip_runtime.h>
#include <cstdint>
#include <cstddef>

#define BB 512   // batch
#define TT 512   // seq len
#define HH 100   // hidden
#define G4 400   // 4*H

// ---------------------------------------------------------------------------
// Recurrent kernel: full 512 steps of one layer in one launch.
// grid = 256 blocks x 448 threads, 1 block/CU, VGPR cap 256.
// Thread map: e = tid/224, off = tid%224, j = off>>1 (unit, active j<100),
// role = off&1. Role A (0) owns gate-rows {j, 200+j} = (i,g); role B (1)
// owns {100+j, 300+j} = (f,o). Both roles: 200 weight floats in VGPRs,
// 25 broadcast ds_read_b128 of own-elem h + 200 FMA per step.
// A computes sig(i)*tanh(g), ships it to B via one shfl_xor(1); B keeps c in
// a register, computes h = sig(o)*tanh(c), writes double-buffered h.
// => NO gate LDS round-trip, ONE __syncthreads per step (vs 2 + gsh before).
// Weights gathered from an LDS staging copy of Whh that is then fully
// clobbered (reused as hbuf) so the compiler cannot remat the gathers.
// All global reads (xc, dmask, x) prefetched one full step ahead.
// ---------------------------------------------------------------------------
template<bool IS_L0, bool WRITE_DROP>
__global__ __launch_bounds__(448, 1)
void rec_kernel(const float* __restrict__ x,       // [B][T] (layer0 input, IN=1)
                const float* __restrict__ xc,      // [T][B][400] (layers>0)
                const float* __restrict__ Whh_l,   // [400][100]
                const float* __restrict__ Wih0,    // [400] (layer0)
                const float* __restrict__ bih_l,   // [400] (layer0)
                const float* __restrict__ bhh_l,   // [400] (layer0)
                const float* __restrict__ dmask_l, // [B][T][100] (if WRITE_DROP)
                float* __restrict__ hdrop,         // [T][B][100] (if WRITE_DROP)
                float* __restrict__ st_h,          // [B][100]
                float* __restrict__ st_c)          // [B][100]
{
    __shared__ float sh[G4 * HH];   // 160,000 B: weight staging, then hbuf
    // hbuf(buf,e,k) = sh[buf*224 + e*112 + k]

    const int tid  = threadIdx.x;
    const int e    = (tid < 224) ? 0 : 1;
    const int off  = tid - e * 224;            // 0..223
    const int j    = off >> 1;                 // 0..111
    const int role = off & 1;                  // 0: (i,g)  1: (f,o)
    const bool active = (j < HH);
    const int jc   = active ? j : (HH - 1);
    const int r0   = role * 100 + jc;          // i- or f-row (sigmoid)
    const int r1   = r0 + 200;                 // g- or o-row (tanh iff role 0)
    const int b    = blockIdx.x * 2 + e;

    // --- stage Whh into LDS (coalesced float4) ---
    {
        const float4* src = (const float4*)Whh_l;
        float4* dst = (float4*)sh;
        for (int i = tid; i < G4 * HH / 4; i += 448) dst[i] = src[i];
    }
    __syncthreads();

    // --- gather this thread's two gate-rows into registers ---
    float4 wf0[25], wf1[25];
    {
        const float4* s0 = (const float4*)&sh[r0 * HH];
        const float4* s1 = (const float4*)&sh[r1 * HH];
        #pragma unroll
        for (int m = 0; m < 25; ++m) { wf0[m] = s0[m]; wf1[m] = s1[m]; }
    }
    __syncthreads();

    // --- clobber ALL of sh: kills remat-from-LDS, zero-inits hbuf ---
    for (int i = tid; i < G4 * HH; i += 448) sh[i] = 0.f;

    float wx0 = 0.f, wx1 = 0.f, bs0 = 0.f, bs1 = 0.f;
    if (IS_L0) {
        wx0 = Wih0[r0];  bs0 = bih_l[r0] + bhh_l[r0];
        wx1 = Wih0[r1];  bs1 = bih_l[r1] + bhh_l[r1];
    }

    const bool isB = (role == 1);
    float c2 = 0.f, hlast = 0.f;

    __syncthreads();

    // --- prefetch t = 0 ---
    float gin0 = 0.f, gin1 = 0.f, xv = 0.f, mk = 0.f;
    if (IS_L0) {
        xv = x[(size_t)b * TT];
    } else {
        gin0 = xc[(size_t)b * G4 + r0];
        gin1 = xc[(size_t)b * G4 + r1];
    }
    if (WRITE_DROP && isB && active) mk = dmask_l[(size_t)b * TT * HH + jc];

    int cur = 0;
    for (int t = 0; t < TT; ++t) {
        const int tn = (t + 1 < TT) ? (t + 1) : t;

        // --- issue prefetches for t+1 ---
        float nxv = 0.f, ngin0 = 0.f, ngin1 = 0.f, nmk = 0.f;
        if (IS_L0) {
            nxv = x[(size_t)b * TT + tn];
        } else {
            const size_t base = (size_t)tn * (BB * G4) + (size_t)b * G4;
            ngin0 = xc[base + r0];
            ngin1 = xc[base + r1];
        }
        if (WRITE_DROP && isB && active)
            nmk = dmask_l[((size_t)b * TT + tn) * HH + jc];

        if (IS_L0) {
            gin0 = fmaf(xv, wx0, bs0);
            gin1 = fmaf(xv, wx1, bs1);
        }

        // --- two gate-row dots over own elem's h (broadcast LDS reads) ---
        float a0 = 0.f, a0b = 0.f, a1 = 0.f, a1b = 0.f;
        {
            const float4* hp = (const float4*)&sh[cur * 224 + e * 112];
            #pragma unroll
            for (int m = 0; m < 25; ++m) {
                const float4 hv = hp[m];
                a0  = fmaf(wf0[m].x, hv.x, a0);
                a0b = fmaf(wf0[m].y, hv.y, a0b);
                a0  = fmaf(wf0[m].z, hv.z, a0);
                a0b = fmaf(wf0[m].w, hv.w, a0b);
                a1  = fmaf(wf1[m].x, hv.x, a1);
                a1b = fmaf(wf1[m].y, hv.y, a1b);
                a1  = fmaf(wf1[m].z, hv.z, a1);
                a1b = fmaf(wf1[m].w, hv.w, a1b);
            }
        }
        const float pre0 = a0 + a0b + gin0;    // i (A) | f (B)
        const float pre1 = a1 + a1b + gin1;    // g (A) | o (B)

        // s0 = sigmoid(pre0); s1 = role A ? tanh(pre1) : sigmoid(pre1)
        const float s0 = 1.f / (1.f + __expf(-pre0));
        const float E1 = __expf(isB ? (-pre1) : (pre1 + pre1));
        const float rr = 1.f / (1.f + E1);
        const float s1 = isB ? rr : fmaf(-2.f, rr, 1.f);

        // A ships sig(i)*tanh(g) to its B partner (adjacent lane)
        const float pv   = s0 * s1;
        const float recv = __shfl_xor(pv, 1);

        const int nxt = cur ^ 1;
        if (isB) {
            c2 = fmaf(s0, c2, recv);                      // c = f*c + i*g
            const float Ec = __expf(c2 + c2);
            const float th = 1.f - 2.f / (Ec + 1.f);      // tanh(c)
            const float h  = s1 * th;                     // o * tanh(c)
            hlast = h;
            if (active) {
                sh[nxt * 224 + e * 112 + j] = h;
                if (WRITE_DROP)
                    hdrop[((size_t)t * BB + b) * HH + j] = h * mk * 2.f;
            }
        }
        __syncthreads();
        cur = nxt;
        gin0 = ngin0; gin1 = ngin1; xv = nxv; mk = nmk;
    }

    if (isB && active) {
        st_h[(size_t)b * HH + j] = hlast;
        st_c[(size_t)b * HH + j] = c2;
    }
}

// ---------------------------------------------------------------------------
// Input-contribution GEMM for layers 1..3 (round-3/4 config, measured 280us):
// xc[m][n] = sum_k A[m][k]*W[n][k] + (bih[n]+bhh[n]), M=T*B=262144, N=400,K=100
// tile 128(M)x64(N), 256 threads, 8x4 microtile, LDS 80 KB -> 2 blocks/CU.
// grid (7, 2048): n-tiles adjacent in dispatch order so the A-tile is L2-hot.
// ---------------------------------------------------------------------------
__global__ __launch_bounds__(256, 2)
void xc_gemm(const float* __restrict__ A,     // [M][100]
             const float* __restrict__ W,     // [400][100]
             const float* __restrict__ bih_l, // [400]
             const float* __restrict__ bhh_l, // [400]
             float* __restrict__ xc)          // [M][400]
{
    __shared__ float At[HH][132];
    __shared__ float Bt[HH][68];

    const int tid = threadIdx.x;
    const int n0  = blockIdx.x * 64;
    const size_t m0 = (size_t)blockIdx.y * 128;

    for (int s = tid; s < 128 * 25; s += 256) {
        const int r = s / 25, kq = s - r * 25;
        const float4 v = *(const float4*)&A[(m0 + r) * HH + kq * 4];
        At[kq * 4 + 0][r] = v.x; At[kq * 4 + 1][r] = v.y;
        At[kq * 4 + 2][r] = v.z; At[kq * 4 + 3][r] = v.w;
    }
    for (int s = tid; s < 64 * 25; s += 256) {
        const int r = s / 25, kq = s - r * 25;
        const int col = n0 + r;
        float4 v = {0.f, 0.f, 0.f, 0.f};
        if (col < G4) v = *(const float4*)&W[(size_t)col * HH + kq * 4];
        Bt[kq * 4 + 0][r] = v.x; Bt[kq * 4 + 1][r] = v.y;
        Bt[kq * 4 + 2][r] = v.z; Bt[kq * 4 + 3][r] = v.w;
    }
    __syncthreads();

    const int tx = tid & 15;   // col group: cols tx*4..+3
    const int ty = tid >> 4;   // row group: rows ty*8..+7
    float acc[8][4];
    #pragma unroll
    for (int i = 0; i < 8; ++i)
        #pragma unroll
        for (int j = 0; j < 4; ++j) acc[i][j] = 0.f;

    #pragma unroll 4
    for (int k = 0; k < HH; ++k) {
        const float4 a0 = *(const float4*)&At[k][ty * 8];
        const float4 a1 = *(const float4*)&At[k][ty * 8 + 4];
        const float4 bv = *(const float4*)&Bt[k][tx * 4];
        const float av[8] = {a0.x, a0.y, a0.z, a0.w, a1.x, a1.y, a1.z, a1.w};
        #pragma unroll
        for (int i = 0; i < 8; ++i) {
            acc[i][0] = fmaf(av[i], bv.x, acc[i][0]);
            acc[i][1] = fmaf(av[i], bv.y, acc[i][1]);
            acc[i][2] = fmaf(av[i], bv.z, acc[i][2]);
            acc[i][3] = fmaf(av[i], bv.w, acc[i][3]);
        }
    }

    const int col = n0 + tx * 4;
    if (col < G4) {
        const float4 u = *(const float4*)&bih_l[col];
        const float4 v = *(const float4*)&bhh_l[col];
        const float4 bias = {u.x + v.x, u.y + v.y, u.z + v.z, u.w + v.w};
        #pragma unroll
        for (int i = 0; i < 8; ++i) {
            const size_t r = m0 + ty * 8 + i;
            float4 o = {acc[i][0] + bias.x, acc[i][1] + bias.y,
                        acc[i][2] + bias.z, acc[i][3] + bias.w};
            *(float4*)&xc[r * G4 + col] = o;
        }
    }
}

// ---------------------------------------------------------------------------
__global__ __launch_bounds__(256)
void out_kernel(const float* __restrict__ st_h3,  // [B][100]
                const float* __restrict__ Wout,   // [100]
                const float* __restrict__ bout,   // [1]
                float* __restrict__ out)          // [B]
{
    const int b = blockIdx.x * 256 + threadIdx.x;
    if (b < BB) {
        float sum = bout[0];
        #pragma unroll 4
        for (int k = 0; k < HH; ++k)
            sum = fmaf(st_h3[(size_t)b * HH + k], Wout[k], sum);
        out[b] = sum;
    }
}

// ---------------------------------------------------------------------------
extern "C" void kernel_launch(void* const* d_in, const int* in_sizes, int n_in,
                              void* d_out, int out_size, void* d_ws, size_t ws_size,
                              hipStream_t stream)
{
    const float* x     = (const float*)d_in[0];  // [512][512][1]
    const float* Wih0  = (const float*)d_in[1];  // [400][1]
    const float* WihR  = (const float*)d_in[2];  // [3][400][100]
    const float* Whh   = (const float*)d_in[3];  // [4][400][100]
    const float* bih   = (const float*)d_in[4];  // [4][400]
    const float* bhh   = (const float*)d_in[5];  // [4][400]
    const float* Wout  = (const float*)d_in[6];  // [1][100]
    const float* bout  = (const float*)d_in[7];  // [1]
    const float* dmask = (const float*)d_in[8];  // [3][512][512][100]
    float* out = (float*)d_out;

    // ws layout (floats): ~526 MB of the 1200 MB workspace
    float* ws    = (float*)d_ws;
    float* xcb   = ws;                                  // T*B*400
    float* hdrop = xcb + (size_t)TT * BB * G4;          // T*B*100
    float* sth   = hdrop + (size_t)TT * BB * HH;        // 4*B*100
    float* stc   = sth + (size_t)4 * BB * HH;           // 4*B*100

    const dim3 rgrid(BB / 2), rblk(448);
    const dim3 ggrid(7, (TT * BB) / 128), gblk(256);

    // layer 0 (input dim 1 fused into rec)
    rec_kernel<true, true><<<rgrid, rblk, 0, stream>>>(
        x, nullptr, Whh, Wih0, bih, bhh, dmask,
        hdrop, sth, stc);
    // layers 1..3
    for (int l = 1; l < 4; ++l) {
        xc_gemm<<<ggrid, gblk, 0, stream>>>(
            hdrop, WihR + (size_t)(l - 1) * G4 * HH,
            bih + l * G4, bhh + l * G4, xcb);
        if (l < 3) {
            rec_kernel<false, true><<<rgrid, rblk, 0, stream>>>(
                nullptr, xcb, Whh + (size_t)l * G4 * HH,
                nullptr, nullptr, nullptr,
                dmask + (size_t)l * BB * TT * HH,
                hdrop, sth + (size_t)l * BB * HH, stc + (size_t)l * BB * HH);
        } else {
            rec_kernel<false, false><<<rgrid, rblk, 0, stream>>>(
                nullptr, xcb, Whh + (size_t)l * G4 * HH,
                nullptr, nullptr, nullptr,
                nullptr,
                nullptr, sth + (size_t)l * BB * HH, stc + (size_t)l * BB * HH);
        }
    }
    out_kernel<<<dim3(2), dim3(256), 0, stream>>>(sth + (size_t)3 * BB * HH, Wout, bout, out);
}